// Round 8
// baseline (877.573 us; speedup 1.0000x reference)
//
#include <hip/hip_runtime.h>
#include <math.h>

#define N_T 80000
#define N_S 160000
#define D_STATE 400
#define D_EMB 350
#define D_DIST 20
#define HDIM 150
#define GI_DIM 1170
#define KP16 1216   // padded K for weights

typedef __attribute__((ext_vector_type(8))) short s16x8;
typedef __attribute__((ext_vector_type(4))) float f32x4;
typedef __attribute__((ext_vector_type(2))) float f32x2;

__device__ __forceinline__ unsigned short f2bf(float f) {
    union { float f; unsigned int u; } c; c.f = f;
    unsigned int u = c.u;
    unsigned int r = (u + 0x7fffu + ((u >> 16) & 1u)) >> 16;  // RNE
    return (unsigned short)r;
}
__device__ __forceinline__ float bf2f(unsigned short h) {
    union { unsigned int u; float f; } c; c.u = ((unsigned int)h) << 16;
    return c.f;
}

// ---------------------------------------------------------------------------
// Weight conversion: f32 [K][150] -> bf16 transposed+padded [160][KP]
// ---------------------------------------------------------------------------
__global__ __launch_bounds__(256) void convert_kernel(
    const float* __restrict__ sW1, const float* __restrict__ sW2, const float* __restrict__ sW3,
    const float* __restrict__ aW1, const float* __restrict__ aW2, const float* __restrict__ aW3,
    unsigned short* __restrict__ w1t_m, unsigned short* __restrict__ w2t_m, unsigned short* __restrict__ w3_m,
    unsigned short* __restrict__ w1t_a, unsigned short* __restrict__ w2t_a, unsigned short* __restrict__ w3_a)
{
    int gid = blockIdx.x * 256 + threadIdx.x;
    const int S1 = 160 * 1216, S2 = 160 * 160, S3 = 160, S4 = 160 * 448, S5 = 160 * 160, S6 = 160;
    if (gid < S1) {
        int n = gid / 1216, k = gid % 1216;
        float v = (k < GI_DIM && n < HDIM) ? sW1[k * HDIM + n] : 0.f;
        w1t_m[gid] = f2bf(v); return;
    } gid -= S1;
    if (gid < S2) {
        int n = gid / 160, k = gid % 160;
        float v = (k < HDIM && n < HDIM) ? sW2[k * HDIM + n] : 0.f;
        w2t_m[gid] = f2bf(v); return;
    } gid -= S2;
    if (gid < S3) { w3_m[gid] = (gid < HDIM) ? f2bf(sW3[gid]) : (unsigned short)0; return; } gid -= S3;
    if (gid < S4) {
        int n = gid / 448, k = gid % 448;
        float v = (k < D_STATE && n < HDIM) ? aW1[k * HDIM + n] : 0.f;
        w1t_a[gid] = f2bf(v); return;
    } gid -= S4;
    if (gid < S5) {
        int n = gid / 160, k = gid % 160;
        float v = (k < HDIM && n < HDIM) ? aW2[k * HDIM + n] : 0.f;
        w2t_a[gid] = f2bf(v); return;
    } gid -= S5;
    if (gid < S6) { w3_a[gid] = (gid < HDIM) ? f2bf(aW3[gid]) : (unsigned short)0; }
}

// ---------------------------------------------------------------------------
// build_win: gather one 8-elem g_i window (proven in round 4).
// ---------------------------------------------------------------------------
__device__ __forceinline__ void build_win(
    int j0, const float* __restrict__ sp1, const float* __restrict__ sp2,
    const float* __restrict__ em1, const float* __restrict__ em2,
    const float* __restrict__ wt, float w0, float w1v, float* v)
{
    if (j0 + 8 <= 400) {
        float4 q0 = *(const float4*)(sp1 + j0);
        float4 q1 = *(const float4*)(sp1 + j0 + 4);
        v[0] = q0.x; v[1] = q0.y; v[2] = q0.z; v[3] = q0.w;
        v[4] = q1.x; v[5] = q1.y; v[6] = q1.z; v[7] = q1.w;
    } else if (j0 >= 400 && j0 + 8 <= 800) {
        const int jj = j0 - 400;
        float4 q0 = *(const float4*)(sp2 + jj);
        float4 q1 = *(const float4*)(sp2 + jj + 4);
        v[0] = q0.x; v[1] = q0.y; v[2] = q0.z; v[3] = q0.w;
        v[4] = q1.x; v[5] = q1.y; v[6] = q1.z; v[7] = q1.w;
    } else if (j0 >= 800 && j0 + 8 <= 1144) {
        const int jj = j0 - 800;
#pragma unroll
        for (int q = 0; q < 4; ++q) {
            float2 ea = *(const float2*)(em1 + jj + 2 * q);
            float2 eb = *(const float2*)(em2 + jj + 2 * q);
            v[2 * q]     = w0 * ea.x + w1v * eb.x;
            v[2 * q + 1] = w0 * ea.y + w1v * eb.y;
        }
    } else {
#pragma unroll
        for (int q = 0; q < 8; ++q) {
            const int j = j0 + q;
            float val;
            if (j < 400) val = sp1[j];
            else if (j < 800) val = sp2[j - 400];
            else if (j < 1150) val = w0 * em1[j - 800] + w1v * em2[j - 800];
            else if (j < GI_DIM) val = wt[j - 1150];
            else val = 0.f;
            v[q] = val;
        }
    }
}

// ---------------------------------------------------------------------------
// Fused v4: one span-row per lane. acc[1][10] (40 AGPR), M-tile 64, 4 waves.
// Per K-tile: stage B (LDS, reg-prefetched), pack per-lane A frags from the
// gathered window (exact MFMA A-layout), nt-store f32 g_i, MFMA.
// ---------------------------------------------------------------------------
__global__ __launch_bounds__(256, 3) void mention_fused64(
    const float* __restrict__ states, const float* __restrict__ embeds,
    const int* __restrict__ starts, const int* __restrict__ widths,
    const float* __restrict__ alfa, const float* __restrict__ wtab,
    const unsigned short* __restrict__ w1t, const float* __restrict__ b1,
    const unsigned short* __restrict__ w2t, const float* __restrict__ b2,
    const unsigned short* __restrict__ w3, const float* __restrict__ b3,
    float* __restrict__ gi, float* __restrict__ out)
{
    __shared__ __align__(16) char smem[21504];  // B tile [160 rows][128B] swz (20480) / h1 [64][336B]

    const int tid = threadIdx.x;
    const int w = tid >> 6;
    const int l = tid & 63;
    const int l15 = l & 15;
    const int lg = l >> 4;
    const int row0 = blockIdx.x * 64;
    const int srow = row0 + w * 16 + l15;   // this lane's span (4 lanes lg=0..3 share it)

    // ---- span prologue ----
    const int i1 = starts[srow];
    const int wdt = widths[srow];
    int i2 = i1 + wdt; if (i2 > N_T - 1) i2 = N_T - 1;
    int ie = i1 + 1;   if (ie > N_T - 1) ie = N_T - 1;
    const float e0 = expf(alfa[i1]);
    const float e1 = (wdt > 0) ? expf(alfa[ie]) : 0.0f;
    const float inv = 1.0f / (e0 + e1);
    const float w0 = e0 * inv, w1v = e1 * inv;
    const float* __restrict__ sp1 = states + (size_t)i1 * D_STATE;
    const float* __restrict__ sp2 = states + (size_t)i2 * D_STATE;
    const float* __restrict__ em1 = embeds + (size_t)i1 * D_EMB;
    const float* __restrict__ em2 = embeds + (size_t)ie * D_EMB;
    const float* __restrict__ wt  = wtab + (size_t)(wdt + 1) * D_DIST;
    float* __restrict__ grow = gi + (size_t)srow * GI_DIM;

    f32x4 acc[10];
#pragma unroll
    for (int nf = 0; nf < 10; ++nf) acc[nf] = (f32x4){0.f, 0.f, 0.f, 0.f};

    // ---- prefetch t=0: B chunks to regs, A windows to regs ----
    s16x8 vb[5];
#pragma unroll
    for (int i = 0; i < 5; ++i) {
        int idx = i * 256 + tid; int n = idx >> 3, s2 = idx & 7;
        vb[i] = *(const s16x8*)(w1t + (size_t)n * KP16 + s2 * 8);
    }
    float ga[2][8];
    build_win(lg * 8,      sp1, sp2, em1, em2, wt, w0, w1v, ga[0]);
    build_win(32 + lg * 8, sp1, sp2, em1, em2, wt, w0, w1v, ga[1]);

    for (int t = 0; t < 19; ++t) {
        __syncthreads();   // all waves done reading previous B tile

        // ---- stage B (swizzled) ----
#pragma unroll
        for (int i = 0; i < 5; ++i) {
            int idx = i * 256 + tid; int n = idx >> 3, s2 = idx & 7;
            *(s16x8*)(smem + n * 128 + ((s2 * 16) ^ ((n & 7) << 4))) = vb[i];
        }
        __syncthreads();

        // ---- pack current A frags + nt-store f32 g_i ----
        s16x8 af[2];
#pragma unroll
        for (int kc = 0; kc < 2; ++kc) {
            const int jw = t * 64 + kc * 32 + lg * 8;
#pragma unroll
            for (int q = 0; q < 8; ++q) af[kc][q] = (short)f2bf(ga[kc][q]);
            if (jw + 8 <= GI_DIM) {
#pragma unroll
                for (int q = 0; q < 4; ++q) {
                    f32x2 p; p.x = ga[kc][2 * q]; p.y = ga[kc][2 * q + 1];
                    __builtin_nontemporal_store(p, (f32x2*)(grow + jw + 2 * q));
                }
            } else if (jw < GI_DIM) {
#pragma unroll
                for (int q = 0; q < 4; ++q) {
                    if (jw + 2 * q + 2 <= GI_DIM) {
                        f32x2 p; p.x = ga[kc][2 * q]; p.y = ga[kc][2 * q + 1];
                        __builtin_nontemporal_store(p, (f32x2*)(grow + jw + 2 * q));
                    }
                }
            }
        }

        // ---- prefetch t+1 (B + gathers land under the MFMAs) ----
        if (t + 1 < 19) {
            const int k0 = (t + 1) * 64;
#pragma unroll
            for (int i = 0; i < 5; ++i) {
                int idx = i * 256 + tid; int n = idx >> 3, s2 = idx & 7;
                vb[i] = *(const s16x8*)(w1t + (size_t)n * KP16 + k0 + s2 * 8);
            }
            build_win(k0 + lg * 8,      sp1, sp2, em1, em2, wt, w0, w1v, ga[0]);
            build_win(k0 + 32 + lg * 8, sp1, sp2, em1, em2, wt, w0, w1v, ga[1]);
        }

        // ---- MFMA: 2 kc x 10 nf, 1 row-frag ----
#pragma unroll
        for (int kc = 0; kc < 2; ++kc) {
            const int inrow = kc * 64 + lg * 16;
#pragma unroll
            for (int nf = 0; nf < 10; ++nf) {
                const int n = nf * 16 + l15;
                s16x8 b = *(const s16x8*)(smem + n * 128 + (inrow ^ ((n & 7) << 4)));
                acc[nf] = __builtin_amdgcn_mfma_f32_16x16x32_bf16(af[kc], b, acc[nf], 0, 0, 0);
            }
        }
    }

    __syncthreads();   // done reading B; reuse smem as h1 [64][336B]

    // ---- h1 = relu(acc + b1) -> LDS bf16 ----
    {
        float b1c[10];
#pragma unroll
        for (int nf = 0; nf < 10; ++nf) {
            int col = nf * 16 + l15;
            b1c[nf] = (col < HDIM) ? b1[col] : 0.f;
        }
#pragma unroll
        for (int nf = 0; nf < 10; ++nf)
#pragma unroll
            for (int r = 0; r < 4; ++r) {
                int row = w * 16 + lg * 4 + r;
                int col = nf * 16 + l15;
                float h = fmaxf(acc[nf][r] + b1c[nf], 0.f);
                if (col < HDIM) *(unsigned short*)(smem + row * 336 + col * 2) = f2bf(h);
                else            *(unsigned short*)(smem + row * 336 + col * 2) = 0;
            }
    }
    __syncthreads();

    // ---- layer 2: h1[16 rows/wave][160] x W2T (B straight from L2) ----
    f32x4 acc2[10];
#pragma unroll
    for (int nf = 0; nf < 10; ++nf) acc2[nf] = (f32x4){0.f, 0.f, 0.f, 0.f};

#pragma unroll
    for (int kc = 0; kc < 5; ++kc) {
        s16x8 a0 = *(const s16x8*)(smem + (w * 16 + l15) * 336 + kc * 64 + lg * 16);
#pragma unroll
        for (int nf = 0; nf < 10; ++nf) {
            const int n = nf * 16 + l15;
            s16x8 b = *(const s16x8*)(w2t + n * 160 + kc * 32 + lg * 8);
            acc2[nf] = __builtin_amdgcn_mfma_f32_16x16x32_bf16(a0, b, acc2[nf], 0, 0, 0);
        }
    }

    // ---- layer 3: score = relu(acc2 + b2) . W3 + b3 ----
    {
        float b2c[10], w3c[10];
#pragma unroll
        for (int nf = 0; nf < 10; ++nf) {
            int col = nf * 16 + l15;
            b2c[nf] = (col < HDIM) ? b2[col] : 0.f;
            w3c[nf] = bf2f(w3[col]);
        }
#pragma unroll
        for (int r = 0; r < 4; ++r) {
            float ps = 0.f;
#pragma unroll
            for (int nf = 0; nf < 10; ++nf)
                ps += fmaxf(acc2[nf][r] + b2c[nf], 0.f) * w3c[nf];
            ps += __shfl_xor(ps, 1);
            ps += __shfl_xor(ps, 2);
            ps += __shfl_xor(ps, 4);
            ps += __shfl_xor(ps, 8);
            if (l15 == 0)
                out[row0 + w * 16 + lg * 4 + r] = ps + b3[0];
        }
    }
}

// ---------------------------------------------------------------------------
// alfa MLP (proven round-2 kernel): A [M][K] f32 -> out [M]
// ---------------------------------------------------------------------------
template <int K, int NT>
__global__ __launch_bounds__(256) void mlp_mfma(
    const float* __restrict__ A,
    const unsigned short* __restrict__ w1t, const float* __restrict__ b1,
    const unsigned short* __restrict__ w2t, const float* __restrict__ b2,
    const unsigned short* __restrict__ w3, const float* __restrict__ b3,
    float* __restrict__ out)
{
    constexpr int KP = NT * 64;
    __shared__ __align__(16) char smem[43008];
    const int SB_OFF = 16384;

    const int tid = threadIdx.x;
    const int w = tid >> 6;
    const int l = tid & 63;
    const int l15 = l & 15;
    const int lg = l >> 4;
    const int row0 = blockIdx.x * 128;

    const int arow = tid >> 1;
    const int acb = (tid & 1) * 32;

    f32x4 acc[2][10];
#pragma unroll
    for (int rf = 0; rf < 2; ++rf)
#pragma unroll
        for (int nf = 0; nf < 10; ++nf) acc[rf][nf] = (f32x4){0.f, 0.f, 0.f, 0.f};

    const int arow_base = w * 32 + l15;
    const int asw = (arow_base & 7) << 4;

    for (int t = 0; t < NT; ++t) {
        const int k0 = t * 64;
        __syncthreads();

        unsigned short tmp[32];
        if (k0 + 64 <= K) {
            const float* src = A + (size_t)(row0 + arow) * K + k0 + acb;
#pragma unroll
            for (int i = 0; i < 16; ++i) {
                float2 v = ((const float2*)src)[i];
                tmp[2 * i] = f2bf(v.x);
                tmp[2 * i + 1] = f2bf(v.y);
            }
        } else {
            const float* arp = A + (size_t)(row0 + arow) * K;
#pragma unroll
            for (int i = 0; i < 32; ++i) {
                int col = k0 + acb + i;
                tmp[i] = (col < K) ? f2bf(arp[col]) : (unsigned short)0;
            }
        }
        {
            const int sw = (arow & 7) << 4;
#pragma unroll
            for (int i = 0; i < 4; ++i) {
                s16x8 pv;
#pragma unroll
                for (int j = 0; j < 8; ++j) pv[j] = (short)tmp[i * 8 + j];
                int inrow = acb * 2 + i * 16;
                *(s16x8*)(smem + arow * 128 + (inrow ^ sw)) = pv;
            }
        }

#pragma unroll
        for (int i = 0; i < 5; ++i) {
            int idx = i * 256 + tid;
            int n = idx >> 3, s2 = idx & 7;
            s16x8 v = *(const s16x8*)(w1t + (size_t)n * KP + k0 + s2 * 8);
            int inrow = s2 * 16;
            *(s16x8*)(smem + SB_OFF + n * 128 + (inrow ^ ((n & 7) << 4))) = v;
        }

        __syncthreads();

#pragma unroll
        for (int kc = 0; kc < 2; ++kc) {
            const int inrowA = kc * 64 + lg * 16;
            s16x8 a0 = *(const s16x8*)(smem + arow_base * 128 + (inrowA ^ asw));
            s16x8 a1 = *(const s16x8*)(smem + arow_base * 128 + 2048 + (inrowA ^ asw));
#pragma unroll
            for (int nf = 0; nf < 10; ++nf) {
                const int n = nf * 16 + l15;
                s16x8 b = *(const s16x8*)(smem + SB_OFF + n * 128 + (inrowA ^ ((n & 7) << 4)));
                acc[0][nf] = __builtin_amdgcn_mfma_f32_16x16x32_bf16(a0, b, acc[0][nf], 0, 0, 0);
                acc[1][nf] = __builtin_amdgcn_mfma_f32_16x16x32_bf16(a1, b, acc[1][nf], 0, 0, 0);
            }
        }
    }

    __syncthreads();

    {
        float b1c[10];
#pragma unroll
        for (int nf = 0; nf < 10; ++nf) {
            int col = nf * 16 + l15;
            b1c[nf] = (col < HDIM) ? b1[col] : 0.f;
        }
#pragma unroll
        for (int rf = 0; rf < 2; ++rf)
#pragma unroll
            for (int nf = 0; nf < 10; ++nf)
#pragma unroll
                for (int r = 0; r < 4; ++r) {
                    int row = w * 32 + rf * 16 + lg * 4 + r;
                    int col = nf * 16 + l15;
                    float h = fmaxf(acc[rf][nf][r] + b1c[nf], 0.f);
                    *(unsigned short*)(smem + row * 336 + col * 2) = f2bf(h);
                }
    }
    __syncthreads();

    f32x4 acc2[2][10];
#pragma unroll
    for (int rf = 0; rf < 2; ++rf)
#pragma unroll
        for (int nf = 0; nf < 10; ++nf) acc2[rf][nf] = (f32x4){0.f, 0.f, 0.f, 0.f};

#pragma unroll
    for (int kc = 0; kc < 5; ++kc) {
        s16x8 a0 = *(const s16x8*)(smem + (w * 32 + l15) * 336 + kc * 64 + lg * 16);
        s16x8 a1 = *(const s16x8*)(smem + (w * 32 + 16 + l15) * 336 + kc * 64 + lg * 16);
#pragma unroll
        for (int nf = 0; nf < 10; ++nf) {
            const int n = nf * 16 + l15;
            s16x8 b = *(const s16x8*)(w2t + n * 160 + kc * 32 + lg * 8);
            acc2[0][nf] = __builtin_amdgcn_mfma_f32_16x16x32_bf16(a0, b, acc2[0][nf], 0, 0, 0);
            acc2[1][nf] = __builtin_amdgcn_mfma_f32_16x16x32_bf16(a1, b, acc2[1][nf], 0, 0, 0);
        }
    }

    {
        float b2c[10], w3c[10];
#pragma unroll
        for (int nf = 0; nf < 10; ++nf) {
            int col = nf * 16 + l15;
            b2c[nf] = (col < HDIM) ? b2[col] : 0.f;
            w3c[nf] = bf2f(w3[col]);
        }
#pragma unroll
        for (int rf = 0; rf < 2; ++rf)
#pragma unroll
            for (int r = 0; r < 4; ++r) {
                float ps = 0.f;
#pragma unroll
                for (int nf = 0; nf < 10; ++nf)
                    ps += fmaxf(acc2[rf][nf][r] + b2c[nf], 0.f) * w3c[nf];
                ps += __shfl_xor(ps, 1);
                ps += __shfl_xor(ps, 2);
                ps += __shfl_xor(ps, 4);
                ps += __shfl_xor(ps, 8);
                if (l15 == 0)
                    out[row0 + w * 32 + rf * 16 + lg * 4 + r] = ps + b3[0];
            }
    }
}

extern "C" void kernel_launch(void* const* d_in, const int* in_sizes, int n_in,
                              void* d_out, int out_size, void* d_ws, size_t ws_size,
                              hipStream_t stream)
{
    const float* states = (const float*)d_in[0];
    const float* embeds = (const float*)d_in[1];
    const int*   starts = (const int*)d_in[2];
    const int*   widths = (const int*)d_in[3];
    const float* aW1 = (const float*)d_in[4];
    const float* ab1 = (const float*)d_in[5];
    const float* aW2 = (const float*)d_in[6];
    const float* ab2 = (const float*)d_in[7];
    const float* aW3 = (const float*)d_in[8];
    const float* ab3 = (const float*)d_in[9];
    const float* wtab = (const float*)d_in[10];
    const float* sW1 = (const float*)d_in[11];
    const float* sb1 = (const float*)d_in[12];
    const float* sW2 = (const float*)d_in[13];
    const float* sb2 = (const float*)d_in[14];
    const float* sW3 = (const float*)d_in[15];
    const float* sb3 = (const float*)d_in[16];

    float* gi = (float*)d_out;
    float* scores = gi + (size_t)N_S * GI_DIM;

    char* ws = (char*)d_ws;
    float* alfa = (float*)ws;                                   // 320000 B
    unsigned short* w1t_m = (unsigned short*)(ws + 320512);     // 389120
    unsigned short* w2t_m = (unsigned short*)(ws + 709632);     // 51200
    unsigned short* w3_m  = (unsigned short*)(ws + 760832);     // 320
    unsigned short* w1t_a = (unsigned short*)(ws + 761344);     // 143360
    unsigned short* w2t_a = (unsigned short*)(ws + 904704);     // 51200
    unsigned short* w3_a  = (unsigned short*)(ws + 955904);     // 320

    // 0) convert/transpose/pad weights to bf16
    convert_kernel<<<1242, 256, 0, stream>>>(sW1, sW2, sW3, aW1, aW2, aW3,
                                             w1t_m, w2t_m, w3_m, w1t_a, w2t_a, w3_a);

    // 1) alfa = attention-MLP(states)
    mlp_mfma<D_STATE, 7><<<N_T / 128, 256, 0, stream>>>(
        states, w1t_a, ab1, w2t_a, ab2, w3_a, ab3, alfa);

    // 2+3) fused v4: g_i gather -> nt-store + per-lane A frags -> 3-layer MLP
    mention_fused64<<<N_S / 64, 256, 0, stream>>>(
        states, embeds, starts, widths, alfa, wtab,
        w1t_m, sb1, w2t_m, sb2, w3_m, sb3, gi, scores);
}

// Round 9
// 550.476 us; speedup vs baseline: 1.5942x; 1.5942x over previous
//
#include <hip/hip_runtime.h>
#include <math.h>

#define N_T 80000
#define N_S 160000
#define D_STATE 400
#define D_EMB 350
#define D_DIST 20
#define HDIM 150
#define GI_DIM 1170
#define KP16 1216   // padded K for weights

typedef __attribute__((ext_vector_type(8))) short s16x8;
typedef __attribute__((ext_vector_type(4))) float f32x4;
typedef __attribute__((ext_vector_type(2))) float f32x2;

__device__ __forceinline__ unsigned short f2bf(float f) {
    union { float f; unsigned int u; } c; c.f = f;
    unsigned int u = c.u;
    unsigned int r = (u + 0x7fffu + ((u >> 16) & 1u)) >> 16;  // RNE
    return (unsigned short)r;
}
__device__ __forceinline__ float bf2f(unsigned short h) {
    union { unsigned int u; float f; } c; c.u = ((unsigned int)h) << 16;
    return c.f;
}

// ---------------------------------------------------------------------------
// Weight conversion: f32 [K][150] -> bf16 transposed+padded [160][KP]
// ---------------------------------------------------------------------------
__global__ __launch_bounds__(256) void convert_kernel(
    const float* __restrict__ sW1, const float* __restrict__ sW2, const float* __restrict__ sW3,
    const float* __restrict__ aW1, const float* __restrict__ aW2, const float* __restrict__ aW3,
    unsigned short* __restrict__ w1t_m, unsigned short* __restrict__ w2t_m, unsigned short* __restrict__ w3_m,
    unsigned short* __restrict__ w1t_a, unsigned short* __restrict__ w2t_a, unsigned short* __restrict__ w3_a)
{
    int gid = blockIdx.x * 256 + threadIdx.x;
    const int S1 = 160 * 1216, S2 = 160 * 160, S3 = 160, S4 = 160 * 448, S5 = 160 * 160, S6 = 160;
    if (gid < S1) {
        int n = gid / 1216, k = gid % 1216;
        float v = (k < GI_DIM && n < HDIM) ? sW1[k * HDIM + n] : 0.f;
        w1t_m[gid] = f2bf(v); return;
    } gid -= S1;
    if (gid < S2) {
        int n = gid / 160, k = gid % 160;
        float v = (k < HDIM && n < HDIM) ? sW2[k * HDIM + n] : 0.f;
        w2t_m[gid] = f2bf(v); return;
    } gid -= S2;
    if (gid < S3) { w3_m[gid] = (gid < HDIM) ? f2bf(sW3[gid]) : (unsigned short)0; return; } gid -= S3;
    if (gid < S4) {
        int n = gid / 448, k = gid % 448;
        float v = (k < D_STATE && n < HDIM) ? aW1[k * HDIM + n] : 0.f;
        w1t_a[gid] = f2bf(v); return;
    } gid -= S4;
    if (gid < S5) {
        int n = gid / 160, k = gid % 160;
        float v = (k < HDIM && n < HDIM) ? aW2[k * HDIM + n] : 0.f;
        w2t_a[gid] = f2bf(v); return;
    } gid -= S5;
    if (gid < S6) { w3_a[gid] = (gid < HDIM) ? f2bf(aW3[gid]) : (unsigned short)0; }
}

// ---------------------------------------------------------------------------
// g_i build (round-7 proven, shadow removed): one wave per span, batched
// float4-window gathers, batched nontemporal f32 stores.
// ---------------------------------------------------------------------------
__global__ __launch_bounds__(256) void gi_build(
    const float* __restrict__ states, const float* __restrict__ embeds,
    const int* __restrict__ starts, const int* __restrict__ widths,
    const float* __restrict__ alfa, const float* __restrict__ wtab,
    float* __restrict__ gi)
{
    const int wave = threadIdx.x >> 6;
    const int lane = threadIdx.x & 63;
    const int s = blockIdx.x * 4 + wave;

    const int i1 = starts[s];
    const int wdt = widths[s];
    int i2 = i1 + wdt; if (i2 > N_T - 1) i2 = N_T - 1;
    int ie = i1 + 1;  if (ie > N_T - 1) ie = N_T - 1;

    const float e0 = expf(alfa[i1]);
    const float e1 = (wdt > 0) ? expf(alfa[ie]) : 0.0f;
    const float inv = 1.0f / (e0 + e1);
    const float w0 = e0 * inv;
    const float w1v = e1 * inv;

    const float* __restrict__ sp1 = states + (size_t)i1 * D_STATE;
    const float* __restrict__ sp2 = states + (size_t)i2 * D_STATE;
    const float* __restrict__ em1 = embeds + (size_t)i1 * D_EMB;
    const float* __restrict__ em2 = embeds + (size_t)ie * D_EMB;
    const float* __restrict__ wt = wtab + (size_t)(wdt + 1) * D_DIST;
    float* __restrict__ grow = gi + (size_t)s * GI_DIM;

    // ---- phase 1: gather 5 float4 windows per lane (loads batched) ----
    float v[5][4];
#pragma unroll
    for (int i = 0; i < 5; ++i) {
        const int j = (i * 64 + lane) * 4;
        if (j + 4 <= 400) {
            float4 q = *(const float4*)(sp1 + j);
            v[i][0] = q.x; v[i][1] = q.y; v[i][2] = q.z; v[i][3] = q.w;
        } else if (j >= 400 && j + 4 <= 800) {
            float4 q = *(const float4*)(sp2 + (j - 400));
            v[i][0] = q.x; v[i][1] = q.y; v[i][2] = q.z; v[i][3] = q.w;
        } else if (j >= 800 && j + 4 <= 1148) {
            const int jj = j - 800;
            float2 a0 = *(const float2*)(em1 + jj);
            float2 a1 = *(const float2*)(em1 + jj + 2);
            float2 b0 = *(const float2*)(em2 + jj);
            float2 b1 = *(const float2*)(em2 + jj + 2);
            v[i][0] = w0 * a0.x + w1v * b0.x;
            v[i][1] = w0 * a0.y + w1v * b0.y;
            v[i][2] = w0 * a1.x + w1v * b1.x;
            v[i][3] = w0 * a1.y + w1v * b1.y;
        } else if (j < KP16) {
#pragma unroll
            for (int q = 0; q < 4; ++q) {
                const int jq = j + q;
                float val;
                if (jq < 400) val = sp1[jq];
                else if (jq < 800) val = sp2[jq - 400];
                else if (jq < 1150) val = w0 * em1[jq - 800] + w1v * em2[jq - 800];
                else if (jq < GI_DIM) val = wt[jq - 1150];
                else val = 0.f;
                v[i][q] = val;
            }
        }
    }

    // ---- phase 2: stores batched (nontemporal f32) ----
#pragma unroll
    for (int i = 0; i < 5; ++i) {
        const int j = (i * 64 + lane) * 4;
        if (j >= KP16) continue;
        if (j + 2 <= GI_DIM) {
            f32x2 p01; p01.x = v[i][0]; p01.y = v[i][1];
            __builtin_nontemporal_store(p01, (f32x2*)(grow + j));
        }
        if (j + 4 <= GI_DIM) {
            f32x2 p23; p23.x = v[i][2]; p23.y = v[i][3];
            __builtin_nontemporal_store(p23, (f32x2*)(grow + j + 2));
        }
    }
}

// ---------------------------------------------------------------------------
// Mention GEMM reading f32 g_i directly (no shadow): round-7 structure,
// A staged as 16x float2 per thread, converted to bf16 at ds_write time.
// ---------------------------------------------------------------------------
__global__ __launch_bounds__(256) void mention_gemm_f32(
    const float* __restrict__ A,
    const unsigned short* __restrict__ w1t, const float* __restrict__ b1,
    const unsigned short* __restrict__ w2t, const float* __restrict__ b2,
    const unsigned short* __restrict__ w3, const float* __restrict__ b3,
    float* __restrict__ out)
{
    __shared__ __align__(16) char smem[43008];
    const int SB_OFF = 16384;

    const int tid = threadIdx.x;
    const int w = tid >> 6;
    const int l = tid & 63;
    const int l15 = l & 15;
    const int lg = l >> 4;
    const int row0 = blockIdx.x * 128;

    const int arow = tid >> 1;          // A-staging: 2 threads per row
    const int acb = (tid & 1) * 32;     // 32 cols each

    f32x4 acc[2][10];
#pragma unroll
    for (int rf = 0; rf < 2; ++rf)
#pragma unroll
        for (int nf = 0; nf < 10; ++nf) acc[rf][nf] = (f32x4){0.f, 0.f, 0.f, 0.f};

    const int arow_base = w * 32 + l15;
    const int asw = (arow_base & 7) << 4;
    const int sw = (arow & 7) << 4;

    // ---- prefetch t=0 ----
    float2 va[16];
    s16x8 vb[5];
    {
        const float* src = A + (size_t)(row0 + arow) * GI_DIM + acb;
#pragma unroll
        for (int i = 0; i < 16; ++i) va[i] = ((const float2*)src)[i];
#pragma unroll
        for (int i = 0; i < 5; ++i) {
            int idx = i * 256 + tid; int n = idx >> 3, s2 = idx & 7;
            vb[i] = *(const s16x8*)(w1t + (size_t)n * KP16 + s2 * 8);
        }
    }

    for (int t = 0; t < 19; ++t) {
        __syncthreads();   // all waves done reading previous LDS tile

        // ---- ds_write staged registers (convert f32->bf16, swizzled) ----
#pragma unroll
        for (int i = 0; i < 4; ++i) {
            s16x8 pv;
#pragma unroll
            for (int q = 0; q < 4; ++q) {
                float2 vv = va[i * 4 + q];
                pv[2 * q]     = (short)f2bf(vv.x);
                pv[2 * q + 1] = (short)f2bf(vv.y);
            }
            int inrow = acb * 2 + i * 16;
            *(s16x8*)(smem + arow * 128 + (inrow ^ sw)) = pv;
        }
#pragma unroll
        for (int i = 0; i < 5; ++i) {
            int idx = i * 256 + tid; int n = idx >> 3, s2 = idx & 7;
            *(s16x8*)(smem + SB_OFF + n * 128 + ((s2 * 16) ^ ((n & 7) << 4))) = vb[i];
        }
        __syncthreads();

        // ---- prefetch t+1 (lands during MFMA phase) ----
        if (t + 1 < 19) {
            const int k0 = (t + 1) * 64;
            if (k0 + 64 <= GI_DIM) {
                const float* src = A + (size_t)(row0 + arow) * GI_DIM + k0 + acb;
#pragma unroll
                for (int i = 0; i < 16; ++i) va[i] = ((const float2*)src)[i];
            } else {
                const float* arp = A + (size_t)(row0 + arow) * GI_DIM;
#pragma unroll
                for (int i = 0; i < 16; ++i) {
                    int c0 = k0 + acb + 2 * i;
                    va[i].x = (c0 < GI_DIM) ? arp[c0] : 0.f;
                    va[i].y = (c0 + 1 < GI_DIM) ? arp[c0 + 1] : 0.f;
                }
            }
#pragma unroll
            for (int i = 0; i < 5; ++i) {
                int idx = i * 256 + tid; int n = idx >> 3, s2 = idx & 7;
                vb[i] = *(const s16x8*)(w1t + (size_t)n * KP16 + k0 + s2 * 8);
            }
        }

        // ---- MFMA phase ----
#pragma unroll
        for (int kc = 0; kc < 2; ++kc) {
            const int inrowA = kc * 64 + lg * 16;
            s16x8 a0 = *(const s16x8*)(smem + arow_base * 128 + (inrowA ^ asw));
            s16x8 a1 = *(const s16x8*)(smem + arow_base * 128 + 2048 + (inrowA ^ asw));
#pragma unroll
            for (int nf = 0; nf < 10; ++nf) {
                const int n = nf * 16 + l15;
                s16x8 b = *(const s16x8*)(smem + SB_OFF + n * 128 + (inrowA ^ ((n & 7) << 4)));
                acc[0][nf] = __builtin_amdgcn_mfma_f32_16x16x32_bf16(a0, b, acc[0][nf], 0, 0, 0);
                acc[1][nf] = __builtin_amdgcn_mfma_f32_16x16x32_bf16(a1, b, acc[1][nf], 0, 0, 0);
            }
        }
    }

    __syncthreads();  // done with sA/sB, reuse as h1 buffer

    // ---- h1 = relu(acc + b1) -> LDS bf16 [128][336B] ----
    {
        float b1c[10];
#pragma unroll
        for (int nf = 0; nf < 10; ++nf) {
            int col = nf * 16 + l15;
            b1c[nf] = (col < HDIM) ? b1[col] : 0.f;
        }
#pragma unroll
        for (int rf = 0; rf < 2; ++rf)
#pragma unroll
            for (int nf = 0; nf < 10; ++nf)
#pragma unroll
                for (int r = 0; r < 4; ++r) {
                    int row = w * 32 + rf * 16 + lg * 4 + r;
                    int col = nf * 16 + l15;
                    float h = fmaxf(acc[rf][nf][r] + b1c[nf], 0.f);
                    *(unsigned short*)(smem + row * 336 + col * 2) = f2bf(h);
                }
    }
    __syncthreads();

    // ---- layer 2 ----
    f32x4 acc2[2][10];
#pragma unroll
    for (int rf = 0; rf < 2; ++rf)
#pragma unroll
        for (int nf = 0; nf < 10; ++nf) acc2[rf][nf] = (f32x4){0.f, 0.f, 0.f, 0.f};

#pragma unroll
    for (int kc = 0; kc < 5; ++kc) {
        s16x8 a0 = *(const s16x8*)(smem + (w * 32 + l15) * 336 + kc * 64 + lg * 16);
        s16x8 a1 = *(const s16x8*)(smem + (w * 32 + 16 + l15) * 336 + kc * 64 + lg * 16);
#pragma unroll
        for (int nf = 0; nf < 10; ++nf) {
            const int n = nf * 16 + l15;
            s16x8 b = *(const s16x8*)(w2t + n * 160 + kc * 32 + lg * 8);
            acc2[0][nf] = __builtin_amdgcn_mfma_f32_16x16x32_bf16(a0, b, acc2[0][nf], 0, 0, 0);
            acc2[1][nf] = __builtin_amdgcn_mfma_f32_16x16x32_bf16(a1, b, acc2[1][nf], 0, 0, 0);
        }
    }

    // ---- layer 3 ----
    {
        float b2c[10], w3c[10];
#pragma unroll
        for (int nf = 0; nf < 10; ++nf) {
            int col = nf * 16 + l15;
            b2c[nf] = (col < HDIM) ? b2[col] : 0.f;
            w3c[nf] = bf2f(w3[col]);
        }
#pragma unroll
        for (int rf = 0; rf < 2; ++rf)
#pragma unroll
            for (int r = 0; r < 4; ++r) {
                float ps = 0.f;
#pragma unroll
                for (int nf = 0; nf < 10; ++nf)
                    ps += fmaxf(acc2[rf][nf][r] + b2c[nf], 0.f) * w3c[nf];
                ps += __shfl_xor(ps, 1);
                ps += __shfl_xor(ps, 2);
                ps += __shfl_xor(ps, 4);
                ps += __shfl_xor(ps, 8);
                if (l15 == 0)
                    out[row0 + w * 32 + rf * 16 + lg * 4 + r] = ps + b3[0];
            }
    }
}

// ---------------------------------------------------------------------------
// alfa MLP (proven round-2 kernel): A [M][K] f32 -> out [M]
// ---------------------------------------------------------------------------
template <int K, int NT>
__global__ __launch_bounds__(256) void mlp_mfma(
    const float* __restrict__ A,
    const unsigned short* __restrict__ w1t, const float* __restrict__ b1,
    const unsigned short* __restrict__ w2t, const float* __restrict__ b2,
    const unsigned short* __restrict__ w3, const float* __restrict__ b3,
    float* __restrict__ out)
{
    constexpr int KP = NT * 64;
    __shared__ __align__(16) char smem[43008];
    const int SB_OFF = 16384;

    const int tid = threadIdx.x;
    const int w = tid >> 6;
    const int l = tid & 63;
    const int l15 = l & 15;
    const int lg = l >> 4;
    const int row0 = blockIdx.x * 128;

    const int arow = tid >> 1;
    const int acb = (tid & 1) * 32;

    f32x4 acc[2][10];
#pragma unroll
    for (int rf = 0; rf < 2; ++rf)
#pragma unroll
        for (int nf = 0; nf < 10; ++nf) acc[rf][nf] = (f32x4){0.f, 0.f, 0.f, 0.f};

    const int arow_base = w * 32 + l15;
    const int asw = (arow_base & 7) << 4;

    for (int t = 0; t < NT; ++t) {
        const int k0 = t * 64;
        __syncthreads();

        unsigned short tmp[32];
        if (k0 + 64 <= K) {
            const float* src = A + (size_t)(row0 + arow) * K + k0 + acb;
#pragma unroll
            for (int i = 0; i < 16; ++i) {
                float2 v = ((const float2*)src)[i];
                tmp[2 * i] = f2bf(v.x);
                tmp[2 * i + 1] = f2bf(v.y);
            }
        } else {
            const float* arp = A + (size_t)(row0 + arow) * K;
#pragma unroll
            for (int i = 0; i < 32; ++i) {
                int col = k0 + acb + i;
                tmp[i] = (col < K) ? f2bf(arp[col]) : (unsigned short)0;
            }
        }
        {
            const int sw = (arow & 7) << 4;
#pragma unroll
            for (int i = 0; i < 4; ++i) {
                s16x8 pv;
#pragma unroll
                for (int j = 0; j < 8; ++j) pv[j] = (short)tmp[i * 8 + j];
                int inrow = acb * 2 + i * 16;
                *(s16x8*)(smem + arow * 128 + (inrow ^ sw)) = pv;
            }
        }

#pragma unroll
        for (int i = 0; i < 5; ++i) {
            int idx = i * 256 + tid;
            int n = idx >> 3, s2 = idx & 7;
            s16x8 v = *(const s16x8*)(w1t + (size_t)n * KP + k0 + s2 * 8);
            int inrow = s2 * 16;
            *(s16x8*)(smem + SB_OFF + n * 128 + (inrow ^ ((n & 7) << 4))) = v;
        }

        __syncthreads();

#pragma unroll
        for (int kc = 0; kc < 2; ++kc) {
            const int inrowA = kc * 64 + lg * 16;
            s16x8 a0 = *(const s16x8*)(smem + arow_base * 128 + (inrowA ^ asw));
            s16x8 a1 = *(const s16x8*)(smem + arow_base * 128 + 2048 + (inrowA ^ asw));
#pragma unroll
            for (int nf = 0; nf < 10; ++nf) {
                const int n = nf * 16 + l15;
                s16x8 b = *(const s16x8*)(smem + SB_OFF + n * 128 + (inrowA ^ ((n & 7) << 4)));
                acc[0][nf] = __builtin_amdgcn_mfma_f32_16x16x32_bf16(a0, b, acc[0][nf], 0, 0, 0);
                acc[1][nf] = __builtin_amdgcn_mfma_f32_16x16x32_bf16(a1, b, acc[1][nf], 0, 0, 0);
            }
        }
    }

    __syncthreads();

    {
        float b1c[10];
#pragma unroll
        for (int nf = 0; nf < 10; ++nf) {
            int col = nf * 16 + l15;
            b1c[nf] = (col < HDIM) ? b1[col] : 0.f;
        }
#pragma unroll
        for (int rf = 0; rf < 2; ++rf)
#pragma unroll
            for (int nf = 0; nf < 10; ++nf)
#pragma unroll
                for (int r = 0; r < 4; ++r) {
                    int row = w * 32 + rf * 16 + lg * 4 + r;
                    int col = nf * 16 + l15;
                    float h = fmaxf(acc[rf][nf][r] + b1c[nf], 0.f);
                    *(unsigned short*)(smem + row * 336 + col * 2) = f2bf(h);
                }
    }
    __syncthreads();

    f32x4 acc2[2][10];
#pragma unroll
    for (int rf = 0; rf < 2; ++rf)
#pragma unroll
        for (int nf = 0; nf < 10; ++nf) acc2[rf][nf] = (f32x4){0.f, 0.f, 0.f, 0.f};

#pragma unroll
    for (int kc = 0; kc < 5; ++kc) {
        s16x8 a0 = *(const s16x8*)(smem + (w * 32 + l15) * 336 + kc * 64 + lg * 16);
        s16x8 a1 = *(const s16x8*)(smem + (w * 32 + 16 + l15) * 336 + kc * 64 + lg * 16);
#pragma unroll
        for (int nf = 0; nf < 10; ++nf) {
            const int n = nf * 16 + l15;
            s16x8 b = *(const s16x8*)(w2t + n * 160 + kc * 32 + lg * 8);
            acc2[0][nf] = __builtin_amdgcn_mfma_f32_16x16x32_bf16(a0, b, acc2[0][nf], 0, 0, 0);
            acc2[1][nf] = __builtin_amdgcn_mfma_f32_16x16x32_bf16(a1, b, acc2[1][nf], 0, 0, 0);
        }
    }

    {
        float b2c[10], w3c[10];
#pragma unroll
        for (int nf = 0; nf < 10; ++nf) {
            int col = nf * 16 + l15;
            b2c[nf] = (col < HDIM) ? b2[col] : 0.f;
            w3c[nf] = bf2f(w3[col]);
        }
#pragma unroll
        for (int rf = 0; rf < 2; ++rf)
#pragma unroll
            for (int r = 0; r < 4; ++r) {
                float ps = 0.f;
#pragma unroll
                for (int nf = 0; nf < 10; ++nf)
                    ps += fmaxf(acc2[rf][nf][r] + b2c[nf], 0.f) * w3c[nf];
                ps += __shfl_xor(ps, 1);
                ps += __shfl_xor(ps, 2);
                ps += __shfl_xor(ps, 4);
                ps += __shfl_xor(ps, 8);
                if (l15 == 0)
                    out[row0 + w * 32 + rf * 16 + lg * 4 + r] = ps + b3[0];
            }
    }
}

extern "C" void kernel_launch(void* const* d_in, const int* in_sizes, int n_in,
                              void* d_out, int out_size, void* d_ws, size_t ws_size,
                              hipStream_t stream)
{
    const float* states = (const float*)d_in[0];
    const float* embeds = (const float*)d_in[1];
    const int*   starts = (const int*)d_in[2];
    const int*   widths = (const int*)d_in[3];
    const float* aW1 = (const float*)d_in[4];
    const float* ab1 = (const float*)d_in[5];
    const float* aW2 = (const float*)d_in[6];
    const float* ab2 = (const float*)d_in[7];
    const float* aW3 = (const float*)d_in[8];
    const float* ab3 = (const float*)d_in[9];
    const float* wtab = (const float*)d_in[10];
    const float* sW1 = (const float*)d_in[11];
    const float* sb1 = (const float*)d_in[12];
    const float* sW2 = (const float*)d_in[13];
    const float* sb2 = (const float*)d_in[14];
    const float* sW3 = (const float*)d_in[15];
    const float* sb3 = (const float*)d_in[16];

    float* gi = (float*)d_out;
    float* scores = gi + (size_t)N_S * GI_DIM;

    char* ws = (char*)d_ws;
    float* alfa = (float*)ws;                                   // 320000 B
    unsigned short* w1t_m = (unsigned short*)(ws + 320512);     // 389120
    unsigned short* w2t_m = (unsigned short*)(ws + 709632);     // 51200
    unsigned short* w3_m  = (unsigned short*)(ws + 760832);     // 320
    unsigned short* w1t_a = (unsigned short*)(ws + 761344);     // 143360
    unsigned short* w2t_a = (unsigned short*)(ws + 904704);     // 51200
    unsigned short* w3_a  = (unsigned short*)(ws + 955904);     // 320

    // 0) convert/transpose/pad weights to bf16
    convert_kernel<<<1242, 256, 0, stream>>>(sW1, sW2, sW3, aW1, aW2, aW3,
                                             w1t_m, w2t_m, w3_m, w1t_a, w2t_a, w3_a);

    // 1) alfa = attention-MLP(states)
    mlp_mfma<D_STATE, 7><<<N_T / 128, 256, 0, stream>>>(
        states, w1t_a, ab1, w2t_a, ab2, w3_a, ab3, alfa);

    // 2) g_i build: f32 output only (no shadow)
    gi_build<<<N_S / 4, 256, 0, stream>>>(
        states, embeds, starts, widths, alfa, wtab, gi);

    // 3) mention GEMM reading f32 g_i directly + MLP layers 2/3
    mention_gemm_f32<<<N_S / 128, 256, 0, stream>>>(
        gi, w1t_m, sb1, w2t_m, sb2, w3_m, sb3, scores);
}